// Round 6
// baseline (14404.852 us; speedup 1.0000x reference)
//
#include <hip/hip_runtime.h>

#define N_PTS 16384
#define M_PTS 4096
#define D_INF 64
#define D_OUTF 128
#define KNN 16
#define DF 67   // 3 + 64

// ---------------- squared norms + float4 pack + sync-tag zero ----------------
__global__ __launch_bounds__(256) void sp_kernel(const float* __restrict__ p,
                                                 float* __restrict__ spn,
                                                 float4* __restrict__ sp4,
                                                 unsigned int* __restrict__ tags) {
  int j = blockIdx.x * 256 + threadIdx.x;
  float a = p[3 * j], b = p[3 * j + 1], c = p[3 * j + 2];
  spn[j] = __fadd_rn(__fadd_rn(__fmul_rn(a, a), __fmul_rn(b, b)), __fmul_rn(c, c));
  sp4[j] = make_float4(a, b, c, 0.f);
  if (j < 128) tags[j] = 0;  // reset cross-block sync tags every launch
}

// ---------------- FPS: 8 blocks x 512 thr x 4 pts, flag-synced ----------------
// R0-R5 lesson: single-CU FPS is memory-traffic-bound (~0.5 MB/iter of point
// state through one CU's L1/LDS ~= 4000 cyc/iter) and 64-128 floats/thread of
// state can never be kept in VGPRs by this allocator. 8 blocks shrink state to
// 20 floats/thread (4 float4 coords + 4 dd) -> pure-register inner loop, and
// the iteration's serial dependency is carried by device-scope tag/slot sync:
// payload stores -> threadfence -> RELEASE tag; readers ACQUIRE-poll 8 tags.
// Slots are parity-double-buffered (64B stride): a parity buffer is rewritten
// only 2 iterations later, after every block consumed it -> no seqlock race.
// All blocks combine identical candidate sets deterministically -> identical
// winner (val, min-idx tie = jnp.argmax first-occurrence) everywhere.
#define FPS_NB 8
#define FPS_BT 512

__global__ __launch_bounds__(FPS_BT) void fps_kernel(
    const float4* __restrict__ sp4, const float* __restrict__ p,
    int* __restrict__ sidx, float* __restrict__ np_out,
    unsigned int* __restrict__ tags, float* __restrict__ slots) {
  const int t = threadIdx.x;
  const int b = blockIdx.x;
  const int lane = t & 63;
  const int w = t >> 6;                 // 8 waves per block
  const int base = b << 11;             // 2048 points per block
  float4 q0 = sp4[base + t];
  float4 q1 = sp4[base + 512 + t];
  float4 q2 = sp4[base + 1024 + t];
  float4 q3 = sp4[base + 1536 + t];
  float dd0 = INFINITY, dd1 = INFINITY, dd2 = INFINITY, dd3 = INFINITY;
  __shared__ float s_loc[8][8];
  __shared__ float s_glob[8][8];
  float lx = p[0], ly = p[1], lz = p[2];
  if (b == 0 && t == 0) {
    sidx[0] = 0;
    np_out[0] = lx; np_out[1] = ly; np_out[2] = lz;
  }
  for (int i = 1; i < M_PTS; ++i) {
    float tv = -INFINITY; int ti = 0x7FFFFFFF;
    float tx = 0.f, ty = 0.f, tz = 0.f;
    // numpy op order: ((dx*dx + dy*dy) + dz*dz), no fma contraction.
    // strict '>' keeps first (smallest j) occurrence of the max: k ascending
    // => j = base + (k<<9) + t ascending per thread.
#define FPS_STEPQ(Q, DD, K)                                                   \
  do {                                                                        \
    float dx = __fsub_rn(Q.x, lx);                                            \
    float dy = __fsub_rn(Q.y, ly);                                            \
    float dz = __fsub_rn(Q.z, lz);                                            \
    float d = __fadd_rn(__fadd_rn(__fmul_rn(dx, dx), __fmul_rn(dy, dy)),      \
                        __fmul_rn(dz, dz));                                   \
    float nd = fminf(DD, d);                                                  \
    DD = nd;                                                                  \
    bool gt = nd > tv;                                                        \
    tv = gt ? nd : tv;                                                        \
    ti = gt ? (base + ((K) << 9) + t) : ti;                                   \
    tx = gt ? Q.x : tx; ty = gt ? Q.y : ty; tz = gt ? Q.z : tz;               \
  } while (0)
    FPS_STEPQ(q0, dd0, 0);
    FPS_STEPQ(q1, dd1, 1);
    FPS_STEPQ(q2, dd2, 2);
    FPS_STEPQ(q3, dd3, 3);
    // wave reduce: max value, tie -> min global index (first-occurrence argmax)
    float rv = tv; int ri = ti; float rx = tx, ry = ty, rz = tz;
#pragma unroll
    for (int off = 32; off >= 1; off >>= 1) {
      float ov = __shfl_xor(rv, off);
      int   oi = __shfl_xor(ri, off);
      float ox = __shfl_xor(rx, off);
      float oy = __shfl_xor(ry, off);
      float oz = __shfl_xor(rz, off);
      bool tk = (ov > rv) || (ov == rv && oi < ri);
      rv = tk ? ov : rv; ri = tk ? oi : ri;
      rx = tk ? ox : rx; ry = tk ? oy : ry; rz = tk ? oz : rz;
    }
    if (lane == 0) {
      s_loc[w][0] = rv; s_loc[w][1] = __int_as_float(ri);
      s_loc[w][2] = rx; s_loc[w][3] = ry; s_loc[w][4] = rz;
    }
    __syncthreads();  // B1: wave candidates visible
    if (t == 0) {
      float bv = s_loc[0][0]; int bi = __float_as_int(s_loc[0][1]);
      float bx = s_loc[0][2], by = s_loc[0][3], bz = s_loc[0][4];
#pragma unroll
      for (int w2 = 1; w2 < 8; ++w2) {
        float ov = s_loc[w2][0]; int oi = __float_as_int(s_loc[w2][1]);
        bool tk = (ov > bv) || (ov == bv && oi < bi);
        bv = tk ? ov : bv; bi = tk ? oi : bi;
        bx = tk ? s_loc[w2][2] : bx;
        by = tk ? s_loc[w2][3] : by;
        bz = tk ? s_loc[w2][4] : bz;
      }
      float* sl = slots + (((i & 1) * FPS_NB + b) << 4);
      sl[0] = bv; sl[1] = __int_as_float(bi);
      sl[2] = bx; sl[3] = by; sl[4] = bz;
      __threadfence();  // payload visible before tag
      __hip_atomic_store(&tags[b << 4], (unsigned int)i,
                         __ATOMIC_RELEASE, __HIP_MEMORY_SCOPE_AGENT);
    }
    if (t < FPS_NB) {
      unsigned int v = __hip_atomic_load(&tags[t << 4], __ATOMIC_ACQUIRE,
                                         __HIP_MEMORY_SCOPE_AGENT);
      int guard = 0;
      while (v < (unsigned int)i) {
        if (++guard > (1 << 26)) break;  // safety valve: fail, don't hang
        v = __hip_atomic_load(&tags[t << 4], __ATOMIC_ACQUIRE,
                              __HIP_MEMORY_SCOPE_AGENT);
      }
      const float* sl = slots + (((i & 1) * FPS_NB + t) << 4);
      s_glob[t][0] = sl[0]; s_glob[t][1] = sl[1];
      s_glob[t][2] = sl[2]; s_glob[t][3] = sl[3]; s_glob[t][4] = sl[4];
    }
    __syncthreads();  // B2: all 8 block candidates staged in LDS
    float gv = s_glob[0][0]; int gi = __float_as_int(s_glob[0][1]); int gw = 0;
#pragma unroll
    for (int b2 = 1; b2 < 8; ++b2) {
      float ov = s_glob[b2][0]; int oi = __float_as_int(s_glob[b2][1]);
      bool tk = (ov > gv) || (ov == gv && oi < gi);
      gv = tk ? ov : gv; gi = tk ? oi : gi; gw = tk ? b2 : gw;
    }
    lx = s_glob[gw][2]; ly = s_glob[gw][3]; lz = s_glob[gw][4];
    if (b == 0 && t == 0) {
      sidx[i] = gi;
      np_out[3 * i] = lx; np_out[3 * i + 1] = ly; np_out[3 * i + 2] = lz;
    }
  }
}

// ---------------- kNN + grouping + maxpool features: one wave per query ----
__global__ __launch_bounds__(256) void knn_feat_kernel(const float* __restrict__ p,
                                                       const float* __restrict__ x,
                                                       const float* __restrict__ spn,
                                                       const int* __restrict__ sidx,
                                                       float* __restrict__ feat) {
  __shared__ float cd[4][256];
  __shared__ int ci[4][256];
  __shared__ int cnt[4];
  __shared__ int s_nn[4][KNN];
  const int w = threadIdx.x >> 6;
  const int lane = threadIdx.x & 63;
  const int q = (blockIdx.x << 2) + w;
  const int qi = sidx[q];
  const float qx = p[3 * qi], qy = p[3 * qi + 1], qz = p[3 * qi + 2];
  const float sn = spn[qi];
  if (lane == 0) cnt[w] = 0;
  // Phase A: per-lane min distance over its 256 candidates
  float lmin = INFINITY;
  for (int it = 0; it < N_PTS / 64; ++it) {
    int j = lane + (it << 6);
    float dot = __fmaf_rn(qz, p[3 * j + 2],
                 __fmaf_rn(qy, p[3 * j + 1], __fmul_rn(qx, p[3 * j])));
    float d2 = __fsub_rn(__fadd_rn(sn, spn[j]), __fmul_rn(2.0f, dot));
    lmin = fminf(lmin, d2);
  }
  // tau = 16th smallest of 64 lane minima (valid upper bound on 16th NN dist)
  float mv = lmin;
  float tau = INFINITY;
#pragma unroll
  for (int r = 0; r < KNN; ++r) {
    float rmin = mv;
#pragma unroll
    for (int off = 32; off >= 1; off >>= 1) rmin = fminf(rmin, __shfl_xor(rmin, off));
    tau = rmin;
    unsigned long long msk = __ballot(mv == rmin);
    if (lane == (int)(__ffsll(msk) - 1)) mv = INFINITY;
  }
  __syncthreads();
  // Phase B: compact all candidates with d2 <= tau (expected ~18-40)
  for (int it = 0; it < N_PTS / 64; ++it) {
    int j = lane + (it << 6);
    float dot = __fmaf_rn(qz, p[3 * j + 2],
                 __fmaf_rn(qy, p[3 * j + 1], __fmul_rn(qx, p[3 * j])));
    float d2 = __fsub_rn(__fadd_rn(sn, spn[j]), __fmul_rn(2.0f, dot));
    if (d2 <= tau) {
      int pos = atomicAdd(&cnt[w], 1);
      if (pos < 256) { cd[w][pos] = d2; ci[w][pos] = j; }
    }
  }
  __syncthreads();
  // Phase C: extract 16 smallest by (value, index) — stable top_k semantics
  int C = min(cnt[w], 256);
  float vv[4]; int ii[4];
#pragma unroll
  for (int s = 0; s < 4; ++s) {
    int pos = lane + (s << 6);
    bool ok = pos < C;
    vv[s] = ok ? cd[w][pos] : INFINITY;
    ii[s] = ok ? ci[w][pos] : 0x7FFFFFFF;
  }
#pragma unroll
  for (int r = 0; r < KNN; ++r) {
    float bv = vv[0]; int bi = ii[0]; int bs = 0;
#pragma unroll
    for (int s = 1; s < 4; ++s) {
      bool tk = (vv[s] < bv) || (vv[s] == bv && ii[s] < bi);
      bv = tk ? vv[s] : bv; bi = tk ? ii[s] : bi; bs = tk ? s : bs;
    }
    float rv = bv; int ri = bi;
#pragma unroll
    for (int off = 32; off >= 1; off >>= 1) {
      float ov = __shfl_xor(rv, off); int oi = __shfl_xor(ri, off);
      bool tk = (ov < rv) || (ov == rv && oi < ri);
      rv = tk ? ov : rv; ri = tk ? oi : ri;
    }
    if (bi == ri) {  // my local-best slot won: retire it
#pragma unroll
      for (int s = 0; s < 4; ++s) if (s == bs) vv[s] = INFINITY;
    }
    if (lane == 0) s_nn[w][r] = ri;
  }
  __syncthreads();
  // Phase D: relative coords, norm scaling, maxpool
  float ax = -INFINITY, ay = -INFINITY, az = -INFINITY, nr = -INFINITY;
  if (lane < KNN) {
    int jn = s_nn[w][lane];
    ax = __fsub_rn(p[3 * jn], qx);
    ay = __fsub_rn(p[3 * jn + 1], qy);
    az = __fsub_rn(p[3 * jn + 2], qz);
    nr = sqrtf(__fadd_rn(__fadd_rn(__fmul_rn(ax, ax), __fmul_rn(ay, ay)),
                         __fmul_rn(az, az)));
  }
  float mnr = nr, mx = ax, my = ay, mz = az;
#pragma unroll
  for (int off = 32; off >= 1; off >>= 1) {
    mnr = fmaxf(mnr, __shfl_xor(mnr, off));
    mx = fmaxf(mx, __shfl_xor(mx, off));
    my = fmaxf(my, __shfl_xor(my, off));
    mz = fmaxf(mz, __shfl_xor(mz, off));
  }
  if (lane == 0) {
    // max over k commutes exactly with the (monotone) division
    float sden = __fadd_rn(mnr, 1e-8f);
    feat[q * DF + 0] = mx / sden;
    feat[q * DF + 1] = my / sden;
    feat[q * DF + 2] = mz / sden;
  }
  float fm = -INFINITY;
#pragma unroll
  for (int k = 0; k < KNN; ++k) {
    int jn = s_nn[w][k];
    fm = fmaxf(fm, x[(jn << 6) + lane]);
  }
  feat[q * DF + 3 + lane] = fm;
}

// ---------------- MLP: h = feat @ W + b ----------------
__global__ __launch_bounds__(128) void mlp_kernel(const float* __restrict__ feat,
                                                  const float* __restrict__ W,
                                                  const float* __restrict__ b,
                                                  float* __restrict__ h) {
  int mrow = blockIdx.x;
  int o = threadIdx.x;
  const float* fr = feat + mrow * DF;
  float acc = b[o];
#pragma unroll
  for (int k = 0; k < DF; ++k) acc = __fmaf_rn(fr[k], W[k * D_OUTF + o], acc);
  h[mrow * D_OUTF + o] = acc;
}

// ---------------- BN column stats (training mode) ----------------
__global__ __launch_bounds__(256) void stats_kernel(const float* __restrict__ h,
                                                    const float* __restrict__ gamma,
                                                    const float* __restrict__ beta,
                                                    float* __restrict__ scsh) {
  int o = blockIdx.x;
  int t = threadIdx.x;
  float s = 0.f, s2 = 0.f;
  for (int mrow = t; mrow < M_PTS; mrow += 256) {
    float v = h[mrow * D_OUTF + o];
    s += v;
    s2 = __fmaf_rn(v, v, s2);
  }
#pragma unroll
  for (int off = 32; off >= 1; off >>= 1) {
    s += __shfl_xor(s, off);
    s2 += __shfl_xor(s2, off);
  }
  __shared__ float as1[4], as2[4];
  if ((t & 63) == 0) { as1[t >> 6] = s; as2[t >> 6] = s2; }
  __syncthreads();
  if (t == 0) {
    float ts = ((as1[0] + as1[1]) + as1[2]) + as1[3];
    float ts2 = ((as2[0] + as2[1]) + as2[2]) + as2[3];
    float mean = ts / (float)M_PTS;
    float var = ts2 / (float)M_PTS - mean * mean;
    var = fmaxf(var, 0.f);
    float sc = gamma[o] / sqrtf(var + 1e-5f);
    scsh[o] = sc;
    scsh[D_OUTF + o] = beta[o] - mean * sc;
  }
}

// ---------------- BN apply + ReLU + n_o ----------------
__global__ __launch_bounds__(256) void bn_kernel(const float* __restrict__ h,
                                                 const float* __restrict__ scsh,
                                                 float* __restrict__ out) {
  int idx = blockIdx.x * 256 + threadIdx.x;
  int o = idx & (D_OUTF - 1);
  float v = __fmaf_rn(h[idx], scsh[o], scsh[D_OUTF + o]);
  out[M_PTS * 3 + idx] = fmaxf(v, 0.f);
  if (idx == 0) out[M_PTS * 3 + M_PTS * D_OUTF] = 4096.0f;  // n_o
}

extern "C" void kernel_launch(void* const* d_in, const int* in_sizes, int n_in,
                              void* d_out, int out_size, void* d_ws, size_t ws_size,
                              hipStream_t stream) {
  const float* p     = (const float*)d_in[0];
  const float* x     = (const float*)d_in[1];
  // d_in[2] = o (offsets) — unused, single cloud
  const float* W     = (const float*)d_in[3];
  const float* b     = (const float*)d_in[4];
  const float* gamma = (const float*)d_in[5];
  const float* beta  = (const float*)d_in[6];
  float* out = (float*)d_out;

  float* wsf  = (float*)d_ws;
  int*   sidx = (int*)d_ws;                    // [4096]
  float* spn  = wsf + 4096;                    // [16384]
  float* feat = spn + N_PTS;                   // [4096 * 67]
  float* h    = feat + M_PTS * DF;             // [4096 * 128]
  float* scsh = h + M_PTS * D_OUTF;            // [256]

  // fps scratch overlaps regions written only AFTER fps completes:
  // sp4 (16384 float4 = 65536 floats) on h (524288 floats);
  // tags (128 u32) + slots (256 floats) on feat (274432 floats).
  float4* sp4        = (float4*)h;
  unsigned int* tags = (unsigned int*)feat;
  float* slots       = feat + 128;

  sp_kernel<<<N_PTS / 256, 256, 0, stream>>>(p, spn, sp4, tags);
  fps_kernel<<<FPS_NB, FPS_BT, 0, stream>>>(sp4, p, sidx, out, tags, slots);
  knn_feat_kernel<<<M_PTS / 4, 256, 0, stream>>>(p, x, spn, sidx, feat);
  mlp_kernel<<<M_PTS, D_OUTF, 0, stream>>>(feat, W, b, h);
  stats_kernel<<<D_OUTF, 256, 0, stream>>>(h, gamma, beta, scsh);
  bn_kernel<<<(M_PTS * D_OUTF) / 256, 256, 0, stream>>>(h, scsh, out);
}

// Round 7
// 9510.023 us; speedup vs baseline: 1.5147x; 1.5147x over previous
//
#include <hip/hip_runtime.h>

#define N_PTS 16384
#define M_PTS 4096
#define D_INF 64
#define D_OUTF 128
#define KNN 16
#define DF 67   // 3 + 64

// ---------------- squared norms of p, numpy op order ----------------
__global__ __launch_bounds__(256) void sp_kernel(const float* __restrict__ p,
                                                 float* __restrict__ spn) {
  int j = blockIdx.x * 256 + threadIdx.x;
  float a = p[3 * j], b = p[3 * j + 1], c = p[3 * j + 2];
  spn[j] = __fadd_rn(__fadd_rn(__fmul_rn(a, a), __fmul_rn(b, b)), __fmul_rn(c, c));
}

// ---------------- FPS: 1 block x 512 thr x 32 pts ----------------
// Ledger R0-R6: 1024-thr variants choke on the DS pipe (~1100 DS issues/iter:
// 3-channel shuffle reduce + 16-entry uniform combine + xy reads = 2.88us/
// iter); multi-block cross-XCD sync costs 3.4us/iter; >=96-float reg state
// always spills. This version: 512 thr, mutable state (z+dd = 64 floats) in
// named float4 fields (fits the ~124-VGPR allocation proven at 512 thr in R0),
// xy read-only in LDS (128 KB, BW floor ~1024 cyc/iter), DS-lean tail: update
// uses 1 base addr + compile-time offsets, reduce carries only (val,idx), the
// unique owner lane publishes (val,idx,z) as one float4, combine reads 8
// float4s. ~420 DS issues/iter. One barrier per iter (parity double-buffer).
#define FPS_T 512
#define FPS_W (FPS_T / 64)

__global__ __launch_bounds__(FPS_T) void fps_kernel(const float* __restrict__ p,
                                                    int* __restrict__ sidx,
                                                    float* __restrict__ np_out) {
  const int t = threadIdx.x;
  __shared__ float2 s_xy[N_PTS];       // 128 KB, read-only after init
  __shared__ float4 s_red[2][FPS_W];   // parity x wave: (val, idx_bits, z, pad)
  float4 z0, z1, z2, z3, z4, z5, z6, z7;
  float4 d0, d1, d2, d3, d4, d5, d6, d7;

#define FPS_LD(ZF, DF_, K)                                           \
  do {                                                               \
    int j = t + ((K) << 9);                                          \
    s_xy[j] = make_float2(p[3 * j], p[3 * j + 1]);                   \
    ZF = p[3 * j + 2];                                               \
    DF_ = INFINITY;                                                  \
  } while (0)

  FPS_LD(z0.x, d0.x, 0);  FPS_LD(z0.y, d0.y, 1);  FPS_LD(z0.z, d0.z, 2);  FPS_LD(z0.w, d0.w, 3);
  FPS_LD(z1.x, d1.x, 4);  FPS_LD(z1.y, d1.y, 5);  FPS_LD(z1.z, d1.z, 6);  FPS_LD(z1.w, d1.w, 7);
  FPS_LD(z2.x, d2.x, 8);  FPS_LD(z2.y, d2.y, 9);  FPS_LD(z2.z, d2.z, 10); FPS_LD(z2.w, d2.w, 11);
  FPS_LD(z3.x, d3.x, 12); FPS_LD(z3.y, d3.y, 13); FPS_LD(z3.z, d3.z, 14); FPS_LD(z3.w, d3.w, 15);
  FPS_LD(z4.x, d4.x, 16); FPS_LD(z4.y, d4.y, 17); FPS_LD(z4.z, d4.z, 18); FPS_LD(z4.w, d4.w, 19);
  FPS_LD(z5.x, d5.x, 20); FPS_LD(z5.y, d5.y, 21); FPS_LD(z5.z, d5.z, 22); FPS_LD(z5.w, d5.w, 23);
  FPS_LD(z6.x, d6.x, 24); FPS_LD(z6.y, d6.y, 25); FPS_LD(z6.z, d6.z, 26); FPS_LD(z6.w, d6.w, 27);
  FPS_LD(z7.x, d7.x, 28); FPS_LD(z7.y, d7.y, 29); FPS_LD(z7.z, d7.z, 30); FPS_LD(z7.w, d7.w, 31);

  if (t == 0) {
    sidx[0] = 0;
    np_out[0] = p[0]; np_out[1] = p[1]; np_out[2] = p[2];
  }
  float lx = p[0], ly = p[1], lz = p[2];
  __syncthreads();  // all xy visible before first pass

  for (int i = 1; i < M_PTS; ++i) {
    float tmax = -INFINITY;
    // numpy op order: ((dx*dx + dy*dy) + dz*dz), no fma contraction.
#define FPS_UPD(ZF, DF_, K)                                                   \
  do {                                                                        \
    float2 xy = s_xy[t + ((K) << 9)];                                         \
    float dx = __fsub_rn(xy.x, lx);                                           \
    float dy = __fsub_rn(xy.y, ly);                                           \
    float dz = __fsub_rn(ZF, lz);                                             \
    float d = __fadd_rn(__fadd_rn(__fmul_rn(dx, dx), __fmul_rn(dy, dy)),      \
                        __fmul_rn(dz, dz));                                   \
    float nd = fminf(DF_, d);                                                 \
    DF_ = nd;                                                                 \
    tmax = fmaxf(tmax, nd);                                                   \
  } while (0)

    FPS_UPD(z0.x, d0.x, 0);  FPS_UPD(z0.y, d0.y, 1);  FPS_UPD(z0.z, d0.z, 2);  FPS_UPD(z0.w, d0.w, 3);
    FPS_UPD(z1.x, d1.x, 4);  FPS_UPD(z1.y, d1.y, 5);  FPS_UPD(z1.z, d1.z, 6);  FPS_UPD(z1.w, d1.w, 7);
    FPS_UPD(z2.x, d2.x, 8);  FPS_UPD(z2.y, d2.y, 9);  FPS_UPD(z2.z, d2.z, 10); FPS_UPD(z2.w, d2.w, 11);
    FPS_UPD(z3.x, d3.x, 12); FPS_UPD(z3.y, d3.y, 13); FPS_UPD(z3.z, d3.z, 14); FPS_UPD(z3.w, d3.w, 15);
    FPS_UPD(z4.x, d4.x, 16); FPS_UPD(z4.y, d4.y, 17); FPS_UPD(z4.z, d4.z, 18); FPS_UPD(z4.w, d4.w, 19);
    FPS_UPD(z5.x, d5.x, 20); FPS_UPD(z5.y, d5.y, 21); FPS_UPD(z5.z, d5.z, 22); FPS_UPD(z5.w, d5.w, 23);
    FPS_UPD(z6.x, d6.x, 24); FPS_UPD(z6.y, d6.y, 25); FPS_UPD(z6.z, d6.z, 26); FPS_UPD(z6.w, d6.w, 27);
    FPS_UPD(z7.x, d7.x, 28); FPS_UPD(z7.y, d7.y, 29); FPS_UPD(z7.z, d7.z, 30); FPS_UPD(z7.w, d7.w, 31);

    // rescan (backward, k=31..0): smallest owned slot achieving tmax; track
    // slot index kk (inline-const cndmask) + its z. j = t + k*512 monotone in
    // k -> first-occurrence argmax within the thread.
    int kk = 0;
    float bz = 0.f;
#define FPS_RSC(ZF, DF_, K)                        \
  do {                                             \
    bool c = (DF_ == tmax);                        \
    kk = c ? (K) : kk;                             \
    bz = c ? ZF : bz;                              \
  } while (0)

    FPS_RSC(z7.w, d7.w, 31); FPS_RSC(z7.z, d7.z, 30); FPS_RSC(z7.y, d7.y, 29); FPS_RSC(z7.x, d7.x, 28);
    FPS_RSC(z6.w, d6.w, 27); FPS_RSC(z6.z, d6.z, 26); FPS_RSC(z6.y, d6.y, 25); FPS_RSC(z6.x, d6.x, 24);
    FPS_RSC(z5.w, d5.w, 23); FPS_RSC(z5.z, d5.z, 22); FPS_RSC(z5.y, d5.y, 21); FPS_RSC(z5.x, d5.x, 20);
    FPS_RSC(z4.w, d4.w, 19); FPS_RSC(z4.z, d4.z, 18); FPS_RSC(z4.y, d4.y, 17); FPS_RSC(z4.x, d4.x, 16);
    FPS_RSC(z3.w, d3.w, 15); FPS_RSC(z3.z, d3.z, 14); FPS_RSC(z3.y, d3.y, 13); FPS_RSC(z3.x, d3.x, 12);
    FPS_RSC(z2.w, d2.w, 11); FPS_RSC(z2.z, d2.z, 10); FPS_RSC(z2.y, d2.y, 9);  FPS_RSC(z2.x, d2.x, 8);
    FPS_RSC(z1.w, d1.w, 7);  FPS_RSC(z1.z, d1.z, 6);  FPS_RSC(z1.y, d1.y, 5);  FPS_RSC(z1.x, d1.x, 4);
    FPS_RSC(z0.w, d0.w, 3);  FPS_RSC(z0.z, d0.z, 2);  FPS_RSC(z0.y, d0.y, 1);  FPS_RSC(z0.x, d0.x, 0);

    const int my_ri = t + (kk << 9);
    // 2-channel wave reduce: max value, tie -> min global index
    float rv = tmax;
    int   ri = my_ri;
#pragma unroll
    for (int off = 32; off >= 1; off >>= 1) {
      float ov = __shfl_xor(rv, off);
      int   oi = __shfl_xor(ri, off);
      bool tk = (ov > rv) || (ov == rv && oi < ri);
      rv = tk ? ov : rv;
      ri = tk ? oi : ri;
    }
    const int par = i & 1;
    // unique owner lane (index is unique) publishes (val, idx, z) in one store
    if (tmax == rv && my_ri == ri) {
      s_red[par][t >> 6] = make_float4(rv, __int_as_float(ri), bz, 0.f);
    }
    __syncthreads();  // only barrier per iteration (parity avoids WAR race)
    float4 e0 = s_red[par][0];
    float gv = e0.x; int gi = __float_as_int(e0.y); float gz = e0.z;
#pragma unroll
    for (int w2 = 1; w2 < FPS_W; ++w2) {
      float4 e = s_red[par][w2];
      float ov = e.x; int oi = __float_as_int(e.y);
      bool tk = (ov > gv) || (ov == gv && oi < gi);
      gv = tk ? ov : gv;
      gi = tk ? oi : gi;
      gz = tk ? e.z : gz;
    }
    float2 wxy = s_xy[gi];  // uniform address -> LDS broadcast
    lx = wxy.x; ly = wxy.y; lz = gz;
    if (t == 0) {
      sidx[i] = gi;
      np_out[3 * i] = lx; np_out[3 * i + 1] = ly; np_out[3 * i + 2] = lz;
    }
  }
}

// ---------------- kNN + grouping + maxpool features: one wave per query ----
__global__ __launch_bounds__(256) void knn_feat_kernel(const float* __restrict__ p,
                                                       const float* __restrict__ x,
                                                       const float* __restrict__ spn,
                                                       const int* __restrict__ sidx,
                                                       float* __restrict__ feat) {
  __shared__ float cd[4][256];
  __shared__ int ci[4][256];
  __shared__ int cnt[4];
  __shared__ int s_nn[4][KNN];
  const int w = threadIdx.x >> 6;
  const int lane = threadIdx.x & 63;
  const int q = (blockIdx.x << 2) + w;
  const int qi = sidx[q];
  const float qx = p[3 * qi], qy = p[3 * qi + 1], qz = p[3 * qi + 2];
  const float sn = spn[qi];
  if (lane == 0) cnt[w] = 0;
  // Phase A: per-lane min distance over its 256 candidates
  float lmin = INFINITY;
  for (int it = 0; it < N_PTS / 64; ++it) {
    int j = lane + (it << 6);
    float dot = __fmaf_rn(qz, p[3 * j + 2],
                 __fmaf_rn(qy, p[3 * j + 1], __fmul_rn(qx, p[3 * j])));
    float d2 = __fsub_rn(__fadd_rn(sn, spn[j]), __fmul_rn(2.0f, dot));
    lmin = fminf(lmin, d2);
  }
  // tau = 16th smallest of 64 lane minima (valid upper bound on 16th NN dist)
  float mv = lmin;
  float tau = INFINITY;
#pragma unroll
  for (int r = 0; r < KNN; ++r) {
    float rmin = mv;
#pragma unroll
    for (int off = 32; off >= 1; off >>= 1) rmin = fminf(rmin, __shfl_xor(rmin, off));
    tau = rmin;
    unsigned long long msk = __ballot(mv == rmin);
    if (lane == (int)(__ffsll(msk) - 1)) mv = INFINITY;
  }
  __syncthreads();
  // Phase B: compact all candidates with d2 <= tau (expected ~18-40)
  for (int it = 0; it < N_PTS / 64; ++it) {
    int j = lane + (it << 6);
    float dot = __fmaf_rn(qz, p[3 * j + 2],
                 __fmaf_rn(qy, p[3 * j + 1], __fmul_rn(qx, p[3 * j])));
    float d2 = __fsub_rn(__fadd_rn(sn, spn[j]), __fmul_rn(2.0f, dot));
    if (d2 <= tau) {
      int pos = atomicAdd(&cnt[w], 1);
      if (pos < 256) { cd[w][pos] = d2; ci[w][pos] = j; }
    }
  }
  __syncthreads();
  // Phase C: extract 16 smallest by (value, index) — stable top_k semantics
  int C = min(cnt[w], 256);
  float vv[4]; int ii[4];
#pragma unroll
  for (int s = 0; s < 4; ++s) {
    int pos = lane + (s << 6);
    bool ok = pos < C;
    vv[s] = ok ? cd[w][pos] : INFINITY;
    ii[s] = ok ? ci[w][pos] : 0x7FFFFFFF;
  }
#pragma unroll
  for (int r = 0; r < KNN; ++r) {
    float bv = vv[0]; int bi = ii[0]; int bs = 0;
#pragma unroll
    for (int s = 1; s < 4; ++s) {
      bool tk = (vv[s] < bv) || (vv[s] == bv && ii[s] < bi);
      bv = tk ? vv[s] : bv; bi = tk ? ii[s] : bi; bs = tk ? s : bs;
    }
    float rv = bv; int ri = bi;
#pragma unroll
    for (int off = 32; off >= 1; off >>= 1) {
      float ov = __shfl_xor(rv, off); int oi = __shfl_xor(ri, off);
      bool tk = (ov < rv) || (ov == rv && oi < ri);
      rv = tk ? ov : rv; ri = tk ? oi : ri;
    }
    if (bi == ri) {  // my local-best slot won: retire it
#pragma unroll
      for (int s = 0; s < 4; ++s) if (s == bs) vv[s] = INFINITY;
    }
    if (lane == 0) s_nn[w][r] = ri;
  }
  __syncthreads();
  // Phase D: relative coords, norm scaling, maxpool
  float ax = -INFINITY, ay = -INFINITY, az = -INFINITY, nr = -INFINITY;
  if (lane < KNN) {
    int jn = s_nn[w][lane];
    ax = __fsub_rn(p[3 * jn], qx);
    ay = __fsub_rn(p[3 * jn + 1], qy);
    az = __fsub_rn(p[3 * jn + 2], qz);
    nr = sqrtf(__fadd_rn(__fadd_rn(__fmul_rn(ax, ax), __fmul_rn(ay, ay)),
                         __fmul_rn(az, az)));
  }
  float mnr = nr, mx = ax, my = ay, mz = az;
#pragma unroll
  for (int off = 32; off >= 1; off >>= 1) {
    mnr = fmaxf(mnr, __shfl_xor(mnr, off));
    mx = fmaxf(mx, __shfl_xor(mx, off));
    my = fmaxf(my, __shfl_xor(my, off));
    mz = fmaxf(mz, __shfl_xor(mz, off));
  }
  if (lane == 0) {
    // max over k commutes exactly with the (monotone) division
    float sden = __fadd_rn(mnr, 1e-8f);
    feat[q * DF + 0] = mx / sden;
    feat[q * DF + 1] = my / sden;
    feat[q * DF + 2] = mz / sden;
  }
  float fm = -INFINITY;
#pragma unroll
  for (int k = 0; k < KNN; ++k) {
    int jn = s_nn[w][k];
    fm = fmaxf(fm, x[(jn << 6) + lane]);
  }
  feat[q * DF + 3 + lane] = fm;
}

// ---------------- MLP: h = feat @ W + b ----------------
__global__ __launch_bounds__(128) void mlp_kernel(const float* __restrict__ feat,
                                                  const float* __restrict__ W,
                                                  const float* __restrict__ b,
                                                  float* __restrict__ h) {
  int mrow = blockIdx.x;
  int o = threadIdx.x;
  const float* fr = feat + mrow * DF;
  float acc = b[o];
#pragma unroll
  for (int k = 0; k < DF; ++k) acc = __fmaf_rn(fr[k], W[k * D_OUTF + o], acc);
  h[mrow * D_OUTF + o] = acc;
}

// ---------------- BN column stats (training mode) ----------------
__global__ __launch_bounds__(256) void stats_kernel(const float* __restrict__ h,
                                                    const float* __restrict__ gamma,
                                                    const float* __restrict__ beta,
                                                    float* __restrict__ scsh) {
  int o = blockIdx.x;
  int t = threadIdx.x;
  float s = 0.f, s2 = 0.f;
  for (int mrow = t; mrow < M_PTS; mrow += 256) {
    float v = h[mrow * D_OUTF + o];
    s += v;
    s2 = __fmaf_rn(v, v, s2);
  }
#pragma unroll
  for (int off = 32; off >= 1; off >>= 1) {
    s += __shfl_xor(s, off);
    s2 += __shfl_xor(s2, off);
  }
  __shared__ float as1[4], as2[4];
  if ((t & 63) == 0) { as1[t >> 6] = s; as2[t >> 6] = s2; }
  __syncthreads();
  if (t == 0) {
    float ts = ((as1[0] + as1[1]) + as1[2]) + as1[3];
    float ts2 = ((as2[0] + as2[1]) + as2[2]) + as2[3];
    float mean = ts / (float)M_PTS;
    float var = ts2 / (float)M_PTS - mean * mean;
    var = fmaxf(var, 0.f);
    float sc = gamma[o] / sqrtf(var + 1e-5f);
    scsh[o] = sc;
    scsh[D_OUTF + o] = beta[o] - mean * sc;
  }
}

// ---------------- BN apply + ReLU + n_o ----------------
__global__ __launch_bounds__(256) void bn_kernel(const float* __restrict__ h,
                                                 const float* __restrict__ scsh,
                                                 float* __restrict__ out) {
  int idx = blockIdx.x * 256 + threadIdx.x;
  int o = idx & (D_OUTF - 1);
  float v = __fmaf_rn(h[idx], scsh[o], scsh[D_OUTF + o]);
  out[M_PTS * 3 + idx] = fmaxf(v, 0.f);
  if (idx == 0) out[M_PTS * 3 + M_PTS * D_OUTF] = 4096.0f;  // n_o
}

extern "C" void kernel_launch(void* const* d_in, const int* in_sizes, int n_in,
                              void* d_out, int out_size, void* d_ws, size_t ws_size,
                              hipStream_t stream) {
  const float* p     = (const float*)d_in[0];
  const float* x     = (const float*)d_in[1];
  // d_in[2] = o (offsets) — unused, single cloud
  const float* W     = (const float*)d_in[3];
  const float* b     = (const float*)d_in[4];
  const float* gamma = (const float*)d_in[5];
  const float* beta  = (const float*)d_in[6];
  float* out = (float*)d_out;

  float* wsf  = (float*)d_ws;
  int*   sidx = (int*)d_ws;                    // [4096]
  float* spn  = wsf + 4096;                    // [16384]
  float* feat = spn + N_PTS;                   // [4096 * 67]
  float* h    = feat + M_PTS * DF;             // [4096 * 128]
  float* scsh = h + M_PTS * D_OUTF;            // [256]

  sp_kernel<<<N_PTS / 256, 256, 0, stream>>>(p, spn);
  fps_kernel<<<1, FPS_T, 0, stream>>>(p, sidx, out);
  knn_feat_kernel<<<M_PTS / 4, 256, 0, stream>>>(p, x, spn, sidx, feat);
  mlp_kernel<<<M_PTS, D_OUTF, 0, stream>>>(feat, W, b, h);
  stats_kernel<<<D_OUTF, 256, 0, stream>>>(h, gamma, beta, scsh);
  bn_kernel<<<(M_PTS * D_OUTF) / 256, 256, 0, stream>>>(h, scsh, out);
}